// Round 4
// baseline (301.878 us; speedup 1.0000x reference)
//
#include <hip/hip_runtime.h>
#include <hip/hip_cooperative_groups.h>
#include <stdint.h>

namespace cg = cooperative_groups;
typedef unsigned long long u64;

#define N 8192
#define NW 128            // 64-bit words per mask row
#define MAX_OUT 256
#define MASK_BYTES ((size_t)N * NW * 8)   // 8 MiB

// ws layout:
//   [0, 8MB)    mask u64[N][NW]
//     overlap (dead before phase 3 writes mask):
//       ws+0    partial16 int[16][8192] (512 KB)  per-j-chunk rank counts
//   +8MB        order  int[N]     32 KB
//   +32KB       s_s    float[N]   32 KB
//   +64KB       bbox   float4[N] 128 KB
//   +192KB      area   float[N]   32 KB
//   +224KB      nvalid int

// ================= Kernel 1: cooperative front (rank + scatter + mask) ========
// 512 blocks x 256 threads, 2 blocks/CU co-resident (small VGPR/LDS → safe).
// Phase 1: block g: j-chunk (g>>5)*512, i-chunk (g&31)*256. Keys computed on
//          the fly from score; counts into partial16 (no atomics, no zeroing).
// Phase 2: blocks 0..31 scatter (rank = sum of 16 partials); block 32 counts
//          nvalid (sorted-desc ⇒ valid prefix length = global count).
// Phase 3: block g owns word w = g&127 for row-bands by = (g>>7)+4k.
//          jb/ja loaded once per block.
__global__ __launch_bounds__(256)
void front_kernel(const float* __restrict__ score, const float* __restrict__ box,
                  int* __restrict__ partial16, u64* __restrict__ mask,
                  int* __restrict__ order, float* __restrict__ s_s,
                  float4* __restrict__ bbox, float* __restrict__ area,
                  int* __restrict__ nvalid) {
    cg::grid_group gridg = cg::this_grid();
    const int tid = threadIdx.x;
    const int g = blockIdx.x;

    __shared__ u64 kj[512];
    __shared__ float4 jb[64];
    __shared__ float  ja[64];
    __shared__ int    red[4];

    // ---------------- Phase 1: partial ranks ----------------
    {
        const int jc = g >> 5;            // 0..15
        const int ic = g & 31;            // 0..31
        const int jbase = jc * 512;
        const int ibase = ic * 256;
        for (int t = tid; t < 512; t += 256) {
            uint32_t sb = __float_as_uint(score[jbase + t]);
            kj[t] = ((u64)(~sb) << 32) | (uint32_t)(jbase + t);
        }
        uint32_t sbi = __float_as_uint(score[ibase + tid]);
        const u64 ki = ((u64)(~sbi) << 32) | (uint32_t)(ibase + tid);
        __syncthreads();
        int c = 0;
        #pragma unroll 16
        for (int j = 0; j < 512; ++j) c += (kj[j] < ki) ? 1 : 0;
        partial16[jc * N + ibase + tid] = c;
    }
    __threadfence();
    gridg.sync();

    // ---------------- Phase 2: scatter + nvalid ----------------
    if (g < 32) {
        const int i = g * 256 + tid;
        int r = 0;
        #pragma unroll 16
        for (int k = 0; k < 16; ++k) r += partial16[k * N + i];
        float s = score[i];
        order[r] = i;
        s_s[r] = s;
        float4 cb = ((const float4*)box)[i * 4];   // first 4 of 16: cx,cy,w,h
        float hw = cb.z * 0.5f, hh = cb.w * 0.5f;
        float x0 = cb.x - hw, y0 = cb.y - hh, x1 = cb.x + hw, y1 = cb.y + hh;
        bbox[r] = make_float4(x0, y0, x1, y1);
        area[r] = (x1 - x0) * (y1 - y0);           // replicate ref: area from xyxy
    } else if (g == 32) {
        int c = 0;
        for (int i = tid; i < N; i += 256) c += (score[i] >= 0.3f) ? 1 : 0;
        for (int off = 32; off; off >>= 1) c += __shfl_down(c, off);
        if ((tid & 63) == 0) red[tid >> 6] = c;
        __syncthreads();
        if (tid == 0) *nvalid = red[0] + red[1] + red[2] + red[3];
    }
    __threadfence();
    gridg.sync();

    // ---------------- Phase 3: suppression bitmask (upper triangle) ----------------
    {
        const int w = g & 127;
        const int by0 = g >> 7;            // 0..3
        const int nv = *nvalid;
        if (w >= by0 * 4) {                // else: all tiles of this block are lower-tri
            if (tid < 64) {
                jb[tid] = bbox[w * 64 + tid];
                ja[tid] = area[w * 64 + tid];
            }
            __syncthreads();
            for (int by = by0; by < 32; by += 4) {
                if (w < by * 4) break;     // by increasing → stays below diagonal
                const int i = by * 256 + tid;
                if (i < nv && w >= (i >> 6)) {
                    float4 a = bbox[i];
                    float  aa = area[i];
                    u64 bits = 0;
                    #pragma unroll 8
                    for (int jj = 0; jj < 64; ++jj) {
                        float4 b = jb[jj];
                        float lx = fmaxf(a.x, b.x), ly = fmaxf(a.y, b.y);
                        float rx = fminf(a.z, b.z), ry = fminf(a.w, b.w);
                        float ww = fmaxf(rx - lx, 0.0f), hh = fmaxf(ry - ly, 0.0f);
                        float inter = ww * hh;
                        float denom = ((aa + ja[jj]) - inter) + 1e-9f;  // exact ref op order
                        float iou = inter / denom;                      // IEEE div, matches np
                        bits |= ((u64)(iou > 0.3f)) << jj;
                    }
                    mask[(size_t)i * NW + w] = bits;
                }
            }
        }
    }
}

// ================= Kernel 2: serial greedy pass (R3: pipelined + DPP OR) ======
struct Pipe { u64 col, s1, s2, g0, g1, g2, g3; };

__device__ __forceinline__ unsigned or_dpp32(unsigned v) {
    v |= (unsigned)__builtin_amdgcn_update_dpp(0, (int)v, 0x111, 0xf, 0xf, true); // row_shr:1
    v |= (unsigned)__builtin_amdgcn_update_dpp(0, (int)v, 0x112, 0xf, 0xf, true); // row_shr:2
    v |= (unsigned)__builtin_amdgcn_update_dpp(0, (int)v, 0x114, 0xf, 0xf, true); // row_shr:4
    v |= (unsigned)__builtin_amdgcn_update_dpp(0, (int)v, 0x118, 0xf, 0xf, true); // row_shr:8
    v |= (unsigned)__builtin_amdgcn_update_dpp(0, (int)v, 0x142, 0xf, 0xf, true); // row_bcast:15
    v |= (unsigned)__builtin_amdgcn_update_dpp(0, (int)v, 0x143, 0xf, 0xf, true); // row_bcast:31
    return v;
}

__device__ __forceinline__ u64 wave_or64(u64 v) {
    unsigned lo = or_dpp32((unsigned)v);
    unsigned hi = or_dpp32((unsigned)(v >> 32));
    unsigned slo = (unsigned)__builtin_amdgcn_readlane((int)lo, 63);
    unsigned shi = (unsigned)__builtin_amdgcn_readlane((int)hi, 63);
    return ((u64)shi << 32) | (u64)slo;
}

__global__ __launch_bounds__(64)
void nms_kernel(const u64* __restrict__ mask, const float* __restrict__ s_s,
                const int* __restrict__ order, const float* __restrict__ box,
                const int* __restrict__ nvalid_p, float* __restrict__ out) {
    const int lane = threadIdx.x;
    const int nv = *nvalid_p;
    const int nblk = (nv + 63) >> 6;
    __shared__ int kpos[MAX_OUT];
    int kcount = 0;
    u64 s1m = 0, s2m = 0, s2m_old = 0;

    Pipe A, B;
    A.col = A.s1 = A.s2 = A.g0 = A.g1 = A.g2 = A.g3 = 0;
    B.col = B.s1 = B.s2 = B.g0 = B.g1 = B.g2 = B.g3 = 0;
    if (nblk > 0) {
        const u64* r = mask + (size_t)lane * NW;
        A.col = r[0];
        if (nblk > 1) A.s1 = r[1];
        if (nblk > 2) A.s2 = r[2];
    }
    if (nblk > 1) {
        const u64* r = mask + (size_t)(64 + lane) * NW;
        B.col = r[1];
        if (nblk > 2) B.s1 = r[2];
        if (nblk > 3) B.s2 = r[3];
    }

    auto step = [&](int b, Pipe& P) -> bool {
        u64 col = P.col, s1v = P.s1, s2v = P.s2;
        u64 x = P.g0 | P.g1 | P.g2 | P.g3 | s1m | s2m_old;
        const int b2 = b + 2;
        P.col = P.s1 = P.s2 = P.g0 = P.g1 = P.g2 = P.g3 = 0;
        if (b2 < nblk) {
            const u64* r = mask + (size_t)((b2 << 6) + lane) * NW;
            P.col = r[b2];
            if (b2 + 1 < nblk) P.s1 = r[b2 + 1];
            if (b2 + 2 < nblk) P.s2 = r[b2 + 2];
            const int kc = kcount;
            if (lane < kc)       P.g0 = mask[(size_t)kpos[lane]       * NW + b2];
            if (lane +  64 < kc) P.g1 = mask[(size_t)kpos[lane +  64] * NW + b2];
            if (lane + 128 < kc) P.g2 = mask[(size_t)kpos[lane + 128] * NW + b2];
            if (lane + 192 < kc) P.g3 = mask[(size_t)kpos[lane + 192] * NW + b2];
        }
        u64 rw = wave_or64(x);
        const int base = b << 6;
        const int rem = nv - base;
        u64 validm = (rem >= 64) ? ~0ull : ((1ull << rem) - 1ull);
        u64 todo = validm & ~rw;
        u64 km = 0;
        while (todo) {
            int l = (int)__builtin_ctzll(todo);
            u64 row_l = __ballot(((col >> l) & 1ull) != 0);
            if (lane == 0) kpos[kcount] = base + l;
            km |= (1ull << l);
            kcount++;
            todo &= ~row_l;
            todo &= ~(1ull << l);
            if (kcount >= MAX_OUT) break;
        }
        u64 keepm = ((km >> lane) & 1ull) ? ~0ull : 0ull;
        s2m_old = s2m;
        s2m = s2v & keepm;
        s1m = s1v & keepm;
        return kcount < MAX_OUT;
    };

    bool run = true;
    for (int b = 0; run && b < nblk; b += 2) {
        run = step(b, A);
        if (run && b + 1 < nblk) run = step(b + 1, B);
    }

    __syncthreads();
    float* out_score = out;
    float* out_box   = out + MAX_OUT;
    float* out_valid = out + MAX_OUT + MAX_OUT * 16;
    const float4* box4 = (const float4*)box;
    float4* ob4 = (float4*)out_box;
    for (int t = lane; t < MAX_OUT; t += 64) {
        if (t < kcount) {
            int p = kpos[t];
            out_score[t] = s_s[p];
            out_valid[t] = 1.0f;
            int oi = order[p];
            #pragma unroll
            for (int q = 0; q < 4; ++q) ob4[t * 4 + q] = box4[oi * 4 + q];
        } else {
            out_score[t] = 0.0f;
            out_valid[t] = 0.0f;
            float4 z = make_float4(0.f, 0.f, 0.f, 0.f);
            #pragma unroll
            for (int q = 0; q < 4; ++q) ob4[t * 4 + q] = z;
        }
    }
}

extern "C" void kernel_launch(void* const* d_in, const int* in_sizes, int n_in,
                              void* d_out, int out_size, void* d_ws, size_t ws_size,
                              hipStream_t stream) {
    const float* score = (const float*)d_in[0];   // (8192,1) f32
    const float* box   = (const float*)d_in[1];   // (8192,16) f32
    char* ws = (char*)d_ws;
    u64*    mask      = (u64*)ws;
    int*    partial16 = (int*)ws;                  // 512 KB, dead before mask written
    int*    order  = (int*)   (ws + MASK_BYTES);
    float*  s_s    = (float*) (ws + MASK_BYTES + 32768);
    float4* bbox   = (float4*)(ws + MASK_BYTES + 65536);
    float*  area   = (float*) (ws + MASK_BYTES + 65536 + 131072);
    int*    nvalid = (int*)   (ws + MASK_BYTES + 65536 + 131072 + 32768);
    float*  outp   = (float*)d_out;

    void* args[] = {(void*)&score, (void*)&box, (void*)&partial16, (void*)&mask,
                    (void*)&order, (void*)&s_s, (void*)&bbox, (void*)&area,
                    (void*)&nvalid};
    hipLaunchCooperativeKernel((const void*)front_kernel, dim3(512), dim3(256),
                               args, 0, stream);
    nms_kernel<<<1, 64, 0, stream>>>(mask, s_s, order, box, nvalid, outp);
}

// Round 5
// 124.737 us; speedup vs baseline: 2.4201x; 2.4201x over previous
//
#include <hip/hip_runtime.h>
#include <stdint.h>

typedef unsigned long long u64;

#define N 8192
#define NW 128            // 64-bit words per mask row
#define MAX_OUT 256
#define MASK_BYTES ((size_t)N * NW * 8)   // 8 MiB

// ws layout:
//   [0, 8MB)    maskT u64[NW][N]  (column-major: maskT[w*N + i])
//   +8MB        order  int[N]     32 KB
//   +32KB       s_s    float[N]   32 KB
//   +64KB       bbox   float4[N] 128 KB
//   +192KB      area   float[N]   32 KB
//   +224KB      nvalid int
// No init needed anywhere: order/s_s/bbox/area fully overwritten (rank is a
// permutation); maskT garbage only in never-read locations (proven harmless
// in nms: garbage bits land outside validm / keepm masks); nvalid written.

// ========== Kernel 1: fused rank + scatter + nvalid (no atomics, no init) ====
// 256 blocks x 1024 threads. Every block stages all 8192 score-bit keys in
// LDS, ranks its 32 rows (32-way j-split within block, LDS psum reduce),
// then threads 0..31 scatter order/s_s/bbox/area. Stable desc sort:
// rank(i) = #{j: s_j > s_i} + #{j < i: s_j == s_i}  (uint bit-pattern order
// valid for non-negative floats; matches argsort(-s, stable)).
__global__ __launch_bounds__(1024)
void rank_fused_kernel(const float* __restrict__ score, const float* __restrict__ box,
                       int* __restrict__ order, float* __restrict__ s_s,
                       float4* __restrict__ bbox, float* __restrict__ area,
                       int* __restrict__ nvalid) {
    __shared__ uint32_t ksc[N];        // 32 KB: all score bit-patterns
    __shared__ int psum[32][33];       // +1 pad
    __shared__ int vpart[16];
    const int tid = threadIdx.x;

    // stage 8 scores/thread (2x float4, coalesced) + count valid
    const float4* s4 = (const float4*)score;
    float4 a = s4[tid * 2], b = s4[tid * 2 + 1];
    ksc[tid * 8 + 0] = __float_as_uint(a.x);
    ksc[tid * 8 + 1] = __float_as_uint(a.y);
    ksc[tid * 8 + 2] = __float_as_uint(a.z);
    ksc[tid * 8 + 3] = __float_as_uint(a.w);
    ksc[tid * 8 + 4] = __float_as_uint(b.x);
    ksc[tid * 8 + 5] = __float_as_uint(b.y);
    ksc[tid * 8 + 6] = __float_as_uint(b.z);
    ksc[tid * 8 + 7] = __float_as_uint(b.w);
    int c = (a.x >= 0.3f) + (a.y >= 0.3f) + (a.z >= 0.3f) + (a.w >= 0.3f)
          + (b.x >= 0.3f) + (b.y >= 0.3f) + (b.z >= 0.3f) + (b.w >= 0.3f);
    for (int off = 32; off; off >>= 1) c += __shfl_down(c, off);
    if ((tid & 63) == 0) vpart[tid >> 6] = c;
    __syncthreads();
    if (blockIdx.x == 0 && tid == 0) {
        int t = 0;
        #pragma unroll
        for (int w = 0; w < 16; ++w) t += vpart[w];
        *nvalid = t;
    }

    // rank: lane-mapping i_local = tid&31 (bank-spread), jg = tid>>5
    const int i_local = tid & 31;
    const int jg = tid >> 5;              // 0..31, uniform-ish per wave
    const int ibase = blockIdx.x * 32;
    const uint32_t si = ksc[ibase + i_local];
    const int i = ibase + i_local;
    int cnt = 0;
    const int j0 = jg * 256;
    #pragma unroll 8
    for (int t = 0; t < 256; ++t) {
        const int j = j0 + t;
        const uint32_t sj = ksc[j];
        cnt += (sj > si || (sj == si && j < i)) ? 1 : 0;
    }
    psum[i_local][jg] = cnt;
    __syncthreads();

    if (tid < 32) {
        int r = 0;
        #pragma unroll
        for (int k = 0; k < 32; ++k) r += psum[tid][k];
        const int ii = ibase + tid;
        order[r] = ii;
        s_s[r] = score[ii];
        float4 cb = ((const float4*)box)[ii * 4];   // first 4 of 16: cx,cy,w,h
        float hw = cb.z * 0.5f, hh = cb.w * 0.5f;
        float x0 = cb.x - hw, y0 = cb.y - hh, x1 = cb.x + hw, y1 = cb.y + hh;
        bbox[r] = make_float4(x0, y0, x1, y1);
        area[r] = (x1 - x0) * (y1 - y0);            // replicate ref: area from xyxy
    }
}

// ========== Kernel 2: suppression bitmask, column-major, div-free fast path ==
// maskT[w*N + i]: coalesced 8B stores (consecutive i per wave).
// iou > 0.3f decided by d = fma(-0.3, denom, inter) with 1e-5 relative guard;
// |d| <= 1e-5*denom (P ~ 2e-5) redone with the exact IEEE divide in a fixup
// loop -> bit-identical to reference semantics.
__global__ __launch_bounds__(256)
void mask_kernel(const float4* __restrict__ bbox, const float* __restrict__ area,
                 const int* __restrict__ nvalid_p, u64* __restrict__ maskT) {
    const int w = blockIdx.x;
    if (w < (int)(blockIdx.y << 2)) return;          // whole block below diagonal
    const int nv = *nvalid_p;
    if ((int)(blockIdx.y * 256) >= nv) return;
    __shared__ float4 jb[64];
    __shared__ float  ja[64];
    if (threadIdx.x < 64) {
        jb[threadIdx.x] = bbox[w * 64 + threadIdx.x];
        ja[threadIdx.x] = area[w * 64 + threadIdx.x];
    }
    __syncthreads();
    const int i = blockIdx.y * 256 + threadIdx.x;
    if (i >= nv) return;
    if (w < (i >> 6)) return;
    float4 aa4 = bbox[i];
    float  aa = area[i];
    u64 bits = 0, fb = 0;
    #pragma unroll 8
    for (int jj = 0; jj < 64; ++jj) {
        float4 b = jb[jj];
        float lx = fmaxf(aa4.x, b.x), ly = fmaxf(aa4.y, b.y);
        float rx = fminf(aa4.z, b.z), ry = fminf(aa4.w, b.w);
        float ww = fmaxf(rx - lx, 0.0f), hh = fmaxf(ry - ly, 0.0f);
        float inter = ww * hh;
        float denom = ((aa + ja[jj]) - inter) + 1e-9f;  // exact ref op order
        float d = fmaf(-0.3f, denom, inter);            // sign decides iou>0.3
        bits |= ((u64)(d > 0.0f)) << jj;
        fb   |= ((u64)(fabsf(d) <= 1e-5f * denom)) << jj;
    }
    if (fb) {   // rare exact-divide fixup (margin 1e-5 >> ulp(0.3f)~3e-8)
        while (fb) {
            int jj = (int)__builtin_ctzll(fb); fb &= fb - 1;
            float4 b = jb[jj];
            float lx = fmaxf(aa4.x, b.x), ly = fmaxf(aa4.y, b.y);
            float rx = fminf(aa4.z, b.z), ry = fminf(aa4.w, b.w);
            float ww = fmaxf(rx - lx, 0.0f), hh = fmaxf(ry - ly, 0.0f);
            float inter = ww * hh;
            float denom = ((aa + ja[jj]) - inter) + 1e-9f;
            float iou = inter / denom;                   // IEEE div, matches np
            bits = (bits & ~(1ull << jj)) | (((u64)(iou > 0.3f)) << jj);
        }
    }
    maskT[(size_t)w * N + i] = bits;                     // coalesced
}

// ========== Kernel 3: serial greedy pass (R3: pipelined + DPP OR), maskT =====
struct Pipe { u64 col, s1, s2, g0, g1, g2, g3; };

__device__ __forceinline__ unsigned or_dpp32(unsigned v) {
    v |= (unsigned)__builtin_amdgcn_update_dpp(0, (int)v, 0x111, 0xf, 0xf, true); // row_shr:1
    v |= (unsigned)__builtin_amdgcn_update_dpp(0, (int)v, 0x112, 0xf, 0xf, true); // row_shr:2
    v |= (unsigned)__builtin_amdgcn_update_dpp(0, (int)v, 0x114, 0xf, 0xf, true); // row_shr:4
    v |= (unsigned)__builtin_amdgcn_update_dpp(0, (int)v, 0x118, 0xf, 0xf, true); // row_shr:8
    v |= (unsigned)__builtin_amdgcn_update_dpp(0, (int)v, 0x142, 0xf, 0xf, true); // row_bcast:15
    v |= (unsigned)__builtin_amdgcn_update_dpp(0, (int)v, 0x143, 0xf, 0xf, true); // row_bcast:31
    return v;
}

__device__ __forceinline__ u64 wave_or64(u64 v) {
    unsigned lo = or_dpp32((unsigned)v);
    unsigned hi = or_dpp32((unsigned)(v >> 32));
    unsigned slo = (unsigned)__builtin_amdgcn_readlane((int)lo, 63);
    unsigned shi = (unsigned)__builtin_amdgcn_readlane((int)hi, 63);
    return ((u64)shi << 32) | (u64)slo;
}

__global__ __launch_bounds__(64)
void nms_kernel(const u64* __restrict__ maskT, const float* __restrict__ s_s,
                const int* __restrict__ order, const float* __restrict__ box,
                const int* __restrict__ nvalid_p, float* __restrict__ out) {
    const int lane = threadIdx.x;
    const int nv = *nvalid_p;
    const int nblk = (nv + 63) >> 6;
    __shared__ int kpos[MAX_OUT];
    int kcount = 0;
    u64 s1m = 0, s2m = 0, s2m_old = 0;

    Pipe A, B;
    A.col = A.s1 = A.s2 = A.g0 = A.g1 = A.g2 = A.g3 = 0;
    B.col = B.s1 = B.s2 = B.g0 = B.g1 = B.g2 = B.g3 = 0;
    if (nblk > 0) {
        A.col = maskT[lane];                                // w=0, rows 0..63
        if (nblk > 1) A.s1 = maskT[(size_t)1 * N + lane];
        if (nblk > 2) A.s2 = maskT[(size_t)2 * N + lane];
    }
    if (nblk > 1) {
        B.col = maskT[(size_t)1 * N + 64 + lane];           // w=1, rows 64..127
        if (nblk > 2) B.s1 = maskT[(size_t)2 * N + 64 + lane];
        if (nblk > 3) B.s2 = maskT[(size_t)3 * N + 64 + lane];
    }

    auto step = [&](int b, Pipe& P) -> bool {
        u64 col = P.col, s1v = P.s1, s2v = P.s2;
        u64 x = P.g0 | P.g1 | P.g2 | P.g3 | s1m | s2m_old;
        const int b2 = b + 2;
        P.col = P.s1 = P.s2 = P.g0 = P.g1 = P.g2 = P.g3 = 0;
        if (b2 < nblk) {
            const int row = (b2 << 6) + lane;
            P.col = maskT[(size_t)b2 * N + row];            // coalesced
            if (b2 + 1 < nblk) P.s1 = maskT[(size_t)(b2 + 1) * N + row];
            if (b2 + 2 < nblk) P.s2 = maskT[(size_t)(b2 + 2) * N + row];
            const int kc = kcount;
            const u64* colw = maskT + (size_t)b2 * N;       // 64KB word-column
            if (lane < kc)       P.g0 = colw[kpos[lane]];
            if (lane +  64 < kc) P.g1 = colw[kpos[lane +  64]];
            if (lane + 128 < kc) P.g2 = colw[kpos[lane + 128]];
            if (lane + 192 < kc) P.g3 = colw[kpos[lane + 192]];
        }
        u64 rw = wave_or64(x);
        const int base = b << 6;
        const int rem = nv - base;
        u64 validm = (rem >= 64) ? ~0ull : ((1ull << rem) - 1ull);
        u64 todo = validm & ~rw;
        u64 km = 0;
        while (todo) {
            int l = (int)__builtin_ctzll(todo);
            u64 row_l = __ballot(((col >> l) & 1ull) != 0);  // in-tile row via symmetry
            if (lane == 0) kpos[kcount] = base + l;
            km |= (1ull << l);
            kcount++;
            todo &= ~row_l;
            todo &= ~(1ull << l);
            if (kcount >= MAX_OUT) break;
        }
        u64 keepm = ((km >> lane) & 1ull) ? ~0ull : 0ull;
        s2m_old = s2m;
        s2m = s2v & keepm;
        s1m = s1v & keepm;
        return kcount < MAX_OUT;
    };

    bool run = true;
    for (int b = 0; run && b < nblk; b += 2) {
        run = step(b, A);
        if (run && b + 1 < nblk) run = step(b + 1, B);
    }

    __syncthreads();
    float* out_score = out;
    float* out_box   = out + MAX_OUT;
    float* out_valid = out + MAX_OUT + MAX_OUT * 16;
    const float4* box4 = (const float4*)box;
    float4* ob4 = (float4*)out_box;
    for (int t = lane; t < MAX_OUT; t += 64) {
        if (t < kcount) {
            int p = kpos[t];
            out_score[t] = s_s[p];
            out_valid[t] = 1.0f;
            int oi = order[p];
            #pragma unroll
            for (int q = 0; q < 4; ++q) ob4[t * 4 + q] = box4[oi * 4 + q];
        } else {
            out_score[t] = 0.0f;
            out_valid[t] = 0.0f;
            float4 z = make_float4(0.f, 0.f, 0.f, 0.f);
            #pragma unroll
            for (int q = 0; q < 4; ++q) ob4[t * 4 + q] = z;
        }
    }
}

extern "C" void kernel_launch(void* const* d_in, const int* in_sizes, int n_in,
                              void* d_out, int out_size, void* d_ws, size_t ws_size,
                              hipStream_t stream) {
    const float* score = (const float*)d_in[0];   // (8192,1) f32
    const float* box   = (const float*)d_in[1];   // (8192,16) f32
    char* ws = (char*)d_ws;
    u64*    maskT  = (u64*)ws;
    int*    order  = (int*)   (ws + MASK_BYTES);
    float*  s_s    = (float*) (ws + MASK_BYTES + 32768);
    float4* bbox   = (float4*)(ws + MASK_BYTES + 65536);
    float*  area   = (float*) (ws + MASK_BYTES + 65536 + 131072);
    int*    nvalid = (int*)   (ws + MASK_BYTES + 65536 + 131072 + 32768);

    rank_fused_kernel<<<256, 1024, 0, stream>>>(score, box, order, s_s, bbox, area, nvalid);
    mask_kernel<<<dim3(128, 32), 256, 0, stream>>>(bbox, area, nvalid, maskT);
    nms_kernel<<<1, 64, 0, stream>>>(maskT, s_s, order, box, nvalid, (float*)d_out);
}